// Round 5
// baseline (248.076 us; speedup 1.0000x reference)
//
#include <hip/hip_runtime.h>
#include <hip/hip_bf16.h>

// ---------------------------------------------------------------------------
// AttentionBlock: B=8, L=1024, C=1024, H=8, ch=128.
// fp32 I/O, bf16 MFMA internal.  Head split is a free flat reinterpret.
// R8 lesson: scattered 2B global stores amplify HBM writes ~10x.
// R9 lesson: launch_bounds floors past VGPR need -> scratch spills (1 GB HBM).
// R13 lesson: M-fast XCD swizzle -> 200MB fetch.  R14: M-band swizzle, 49MB.
// R15 lesson: 2 blocks/CU moved MfmaUtil only 31->35.5 (878 TF = exactly the
//      2-barrier-per-K-step structure ceiling ~900 TF).  Block count is not
//      the lever; the phase schedule is (m201: 62% at 1 block/CU).
// R16: m201-style phase schedule for gemm_qkv.  256x128 tile, 512 thr,
//      3-buffer LDS rotation (144 KB): read buf(t%3), stage t+2 into
//      buf((t+2)%3) -- disjoint from both live read buffers, so staging
//      overlaps phases with no mid-iter free-sync.  2 phases/K-tile, each
//      {8 ds_read + 3 stage-issue, barrier, lgkm(0), setprio+16 MFMA,
//      barrier}; one vmcnt(6) per iter (T4), never 0 in steady state.
// ---------------------------------------------------------------------------

typedef __attribute__((ext_vector_type(8))) short short8;
typedef __attribute__((ext_vector_type(4))) float f32x4;

#define QK_SCALE 0.29730177875068026f  // 128^-0.25

__device__ __forceinline__ float bf2f(ushort u) {
    union { float f; unsigned int i; } c; c.i = ((unsigned int)u) << 16; return c.f;
}
__device__ __forceinline__ ushort f2bf(float f) {
    union { float f; unsigned int i; } c; c.f = f;
    unsigned int x = c.i;
    return (ushort)((x + 0x7FFFu + ((x >> 16) & 1u)) >> 16);  // RNE
}

// async 16B global->LDS (m97; LDS dest must be wave-uniform base + lane*16)
__device__ __forceinline__ void gload_lds16(const ushort* g, ushort* l) {
    __builtin_amdgcn_global_load_lds(
        (const __attribute__((address_space(1))) unsigned int*)g,
        (__attribute__((address_space(3))) unsigned int*)l, 16, 0, 0);
}

// ---------------------------------------------------------------------------
// Prep kernel: LN row-per-wave (blocks 0..2047, 4 rows/block, no barriers)
// + w_qkv transpose tiles (2048..5119) + w_out transpose (5120..6143).
// ---------------------------------------------------------------------------
__global__ __launch_bounds__(256) void prep_kernel(
    const float* __restrict__ x, const float* __restrict__ g,
    const float* __restrict__ b, ushort* __restrict__ xn,
    const float* __restrict__ w_qkv, ushort* __restrict__ wqkvT,
    const float* __restrict__ w_out, ushort* __restrict__ woutT) {
    __shared__ ushort t[32][33];
    int bid = blockIdx.x;
    int tid = threadIdx.x;
    if (bid < 2048) {
        // ---- LayerNorm: one row per wave ----
        int w = tid >> 6, lane = tid & 63;
        int row = bid * 4 + w;
        const float* xr = x + (size_t)row * 1024;
        float v[4][4];
        float s1 = 0.f, s2 = 0.f;
#pragma unroll
        for (int j = 0; j < 4; j++) {
            float4 t4 = *(const float4*)(xr + lane * 4 + j * 256);
            v[j][0] = t4.x; v[j][1] = t4.y; v[j][2] = t4.z; v[j][3] = t4.w;
#pragma unroll
            for (int e = 0; e < 4; e++) { s1 += v[j][e]; s2 += v[j][e] * v[j][e]; }
        }
#pragma unroll
        for (int m = 32; m >= 1; m >>= 1) { s1 += __shfl_xor(s1, m); s2 += __shfl_xor(s2, m); }
        float mu = s1 * (1.0f / 1024.0f);
        float var = s2 * (1.0f / 1024.0f) - mu * mu;
        float rs = rsqrtf(var + 1e-5f);
#pragma unroll
        for (int j = 0; j < 4; j++) {
            int c0 = lane * 4 + j * 256;
            float4 gg = *(const float4*)(g + c0);
            float4 bb = *(const float4*)(b + c0);
            float gA[4] = {gg.x, gg.y, gg.z, gg.w};
            float bA[4] = {bb.x, bb.y, bb.z, bb.w};
            ushort o[4];
#pragma unroll
            for (int e = 0; e < 4; e++) o[e] = f2bf((v[j][e] - mu) * rs * gA[e] + bA[e]);
            uint2 pk;
            pk.x = (uint)o[0] | ((uint)o[1] << 16);
            pk.y = (uint)o[2] | ((uint)o[3] << 16);
            *(uint2*)(xn + (size_t)row * 1024 + c0) = pk;
        }
    } else {
        // ---- weight transpose tile ----
        const float* in; ushort* out; int R, Cc, bx, by;
        if (bid < 5120) {
            int tt = bid - 2048;
            in = w_qkv; out = wqkvT; R = 1024; Cc = 3072;
            bx = (tt % 96) * 32; by = (tt / 96) * 32;
        } else {
            int tt = bid - 5120;
            in = w_out; out = woutT; R = 1024; Cc = 1024;
            bx = (tt % 32) * 32; by = (tt / 32) * 32;
        }
        int tx = tid & 31, ty = tid >> 5;
#pragma unroll
        for (int j = 0; j < 32; j += 8)
            t[ty + j][tx] = f2bf(in[(size_t)(by + ty + j) * Cc + bx + tx]);
        __syncthreads();
#pragma unroll
        for (int j = 0; j < 32; j += 8)
            out[(size_t)(bx + ty + j) * R + by + tx] = t[tx][ty + j];
    }
}

// ---------------------------------------------------------------------------
// Per-head bf16 transpose: in [64][1024][128] -> out [64][128][1024]
// ---------------------------------------------------------------------------
__global__ __launch_bounds__(256) void transpose_head(
    const ushort* __restrict__ in, ushort* __restrict__ out) {
    __shared__ ushort t[32][33];
    int h = blockIdx.z;
    int j0 = blockIdx.y * 32;  // seq pos
    int d0 = blockIdx.x * 32;  // head dim
    int tx = threadIdx.x & 31, ty = threadIdx.x >> 5;
    const ushort* src = in + (size_t)h * 131072;
    ushort* dst = out + (size_t)h * 131072;
#pragma unroll
    for (int j = 0; j < 32; j += 8)
        t[ty + j][tx] = src[(size_t)(j0 + ty + j) * 128 + d0 + tx];
    __syncthreads();
#pragma unroll
    for (int j = 0; j < 32; j += 8)
        dst[(size_t)(d0 + ty + j) * 1024 + j0 + tx] = t[tx][ty + j];
}

// ---------------------------------------------------------------------------
// QKV GEMM R16: C[8192,3072] = A[8192,1024] @ Bt[3072,1024]^T.
// 256x128 tile, BK=64, 512 thr = 8 waves (4M x 2N, 64x64 out per wave).
// LDS 144 KB: AS[3][256x64] + BS[3][128x64], 3-buffer rotation:
//   iter t reads buf(t%3), stages tile t+2 into buf((t+2)%3) (disjoint).
// Per K-tile, 2 phases (m201 discipline, 16 MFMA per phase per wave):
//   phase: {8 ds_read (kk frags), 3 gload_lds (stage t+2), s_barrier,
//           lgkmcnt(0), setprio(1), 16 MFMA, setprio(0), s_barrier}
// Iter end: vmcnt(6) (drains exactly tile t+1's 6 loads; 12 outstanding),
// vmcnt(0) only at t=14.  XOR-8 chunk swizzle (conflict-free, measured).
// Grid 768 = 3 exact CU waves; XCD x owns M-tiles [4x,4x+4) (2MB A band).
// ---------------------------------------------------------------------------
__global__ __launch_bounds__(512, 2) void gemm_qkv(
    const ushort* __restrict__ A, const ushort* __restrict__ Bt,
    const float* __restrict__ bias, ushort* __restrict__ out0,
    ushort* __restrict__ out1, ushort* __restrict__ out2) {
    __shared__ __align__(16) ushort AS[3][256 * 64];  // 96 KB
    __shared__ __align__(16) ushort BS[3][128 * 64];  // 48 KB

    int tid = threadIdx.x;
    int lane = tid & 63, w = tid >> 6;       // 8 waves
    int l15 = lane & 15, q4 = lane >> 4;
    int wrM = (w >> 1) * 64;                 // wave M offset: 0/64/128/192
    int wcN = (w & 1) * 64;                  // wave N offset: 0/64

    // R14-proven XCD swizzle: XCD x owns M-tiles 4x..4x+3 (2MB A band,
    // L2-resident for the whole kernel); N-fastest within the band.
    int bid = blockIdx.x;
    int xcd = bid & 7;
    int ib = bid >> 3;                       // 0..95
    int by = xcd * 4 + (ib & 3);             // M-tile 0..31
    int bx = ib >> 2;                        // N-tile 0..23
    int rowBase = by * 256, colBase = bx * 128;

    const ushort* Ab = A + (size_t)rowBase * 1024;
    const ushort* Bb = Bt + (size_t)colBase * 1024;

    // per-thread staging sources (r,l fixed per thread); advance 64/tile.
    const ushort *gA0, *gA1, *gA2, *gA3, *gB0, *gB1;
    {
        int c, r, l;
        c = tid;        r = c >> 3; l = (c & 7) ^ (r & 7); gA0 = Ab + (size_t)r * 1024 + l * 8;
        c = 512 + tid;  r = c >> 3; l = (c & 7) ^ (r & 7); gA1 = Ab + (size_t)r * 1024 + l * 8;
        c = 1024 + tid; r = c >> 3; l = (c & 7) ^ (r & 7); gA2 = Ab + (size_t)r * 1024 + l * 8;
        c = 1536 + tid; r = c >> 3; l = (c & 7) ^ (r & 7); gA3 = Ab + (size_t)r * 1024 + l * 8;
        c = tid;        r = c >> 3; l = (c & 7) ^ (r & 7); gB0 = Bb + (size_t)r * 1024 + l * 8;
        c = 512 + tid;  r = c >> 3; l = (c & 7) ^ (r & 7); gB1 = Bb + (size_t)r * 1024 + l * 8;
    }
    // LDS chunk offsets (ushorts)
    int oA0 = tid * 8, oA1 = (512 + tid) * 8, oA2 = (1024 + tid) * 8, oA3 = (1536 + tid) * 8;
    int oB0 = tid * 8, oB1 = (512 + tid) * 8;

    f32x4 acc[4][4];
    f32x4 zero = {0.f, 0.f, 0.f, 0.f};
#pragma unroll
    for (int mi = 0; mi < 4; mi++)
#pragma unroll
        for (int ni = 0; ni < 4; ni++) acc[mi][ni] = zero;

    // prologue: stage tile0 -> buf0, tile1 -> buf1 (12 loads); wait tile0.
    gload_lds16(gA0, &AS[0][oA0]); gload_lds16(gA1, &AS[0][oA1]);
    gload_lds16(gA2, &AS[0][oA2]); gload_lds16(gA3, &AS[0][oA3]);
    gload_lds16(gB0, &BS[0][oB0]); gload_lds16(gB1, &BS[0][oB1]);
    gA0 += 64; gA1 += 64; gA2 += 64; gA3 += 64; gB0 += 64; gB1 += 64;
    gload_lds16(gA0, &AS[1][oA0]); gload_lds16(gA1, &AS[1][oA1]);
    gload_lds16(gA2, &AS[1][oA2]); gload_lds16(gA3, &AS[1][oA3]);
    gload_lds16(gB0, &BS[1][oB0]); gload_lds16(gB1, &BS[1][oB1]);
    gA0 += 64; gA1 += 64; gA2 += 64; gA3 += 64; gB0 += 64; gB1 += 64;
    asm volatile("s_waitcnt vmcnt(6)" ::: "memory");
    __builtin_amdgcn_s_barrier();

    ushort* rA = &AS[0][0]; ushort* rB = &BS[0][0];   // read (tile t)
    ushort* nA = &AS[1][0]; ushort* nB = &BS[1][0];   // next (tile t+1)
    ushort* sA = &AS[2][0]; ushort* sB = &BS[2][0];   // stage (tile t+2)

    for (int t = 0; t < 16; ++t) {
        const bool doStage = (t < 14);
        short8 aF[4], bF[4];

        // ======== phase 0: kk=0 ========
#pragma unroll
        for (int mi = 0; mi < 4; mi++) {
            int r = wrM + mi * 16 + l15;
            aF[mi] = *(const short8*)&rA[r * 64 + (q4 ^ (r & 7)) * 8];
        }
#pragma unroll
        for (int ni = 0; ni < 4; ni++) {
            int r = wcN + ni * 16 + l15;
            bF[ni] = *(const short8*)&rB[r * 64 + (q4 ^ (r & 7)) * 8];
        }
        if (doStage) {
            gload_lds16(gA0, sA + oA0);
            gload_lds16(gA1, sA + oA1);
            gload_lds16(gA2, sA + oA2);
        }
        __builtin_amdgcn_s_barrier();
        asm volatile("s_waitcnt lgkmcnt(0)" ::: "memory");
        __builtin_amdgcn_s_setprio(1);
#pragma unroll
        for (int mi = 0; mi < 4; mi++)
#pragma unroll
            for (int ni = 0; ni < 4; ni++)
                acc[mi][ni] = __builtin_amdgcn_mfma_f32_16x16x32_bf16(
                    aF[mi], bF[ni], acc[mi][ni], 0, 0, 0);
        __builtin_amdgcn_s_setprio(0);
        __builtin_amdgcn_s_barrier();

        // ======== phase 1: kk=1 ========
#pragma unroll
        for (int mi = 0; mi < 4; mi++) {
            int r = wrM + mi * 16 + l15;
            aF[mi] = *(const short8*)&rA[r * 64 + ((4 + q4) ^ (r & 7)) * 8];
        }
#pragma unroll
        for (int ni = 0; ni < 4; ni++) {
            int r = wcN + ni * 16 + l15;
            bF[ni] = *(const short8*)&rB[r * 64 + ((4 + q4) ^ (r & 7)) * 8];
        }
        if (doStage) {
            gload_lds16(gA3, sA + oA3);
            gload_lds16(gB0, sB + oB0);
            gload_lds16(gB1, sB + oB1);
            gA0 += 64; gA1 += 64; gA2 += 64; gA3 += 64; gB0 += 64; gB1 += 64;
        }
        __builtin_amdgcn_s_barrier();
        asm volatile("s_waitcnt lgkmcnt(0)" ::: "memory");
        __builtin_amdgcn_s_setprio(1);
#pragma unroll
        for (int mi = 0; mi < 4; mi++)
#pragma unroll
            for (int ni = 0; ni < 4; ni++)
                acc[mi][ni] = __builtin_amdgcn_mfma_f32_16x16x32_bf16(
                    aF[mi], bF[ni], acc[mi][ni], 0, 0, 0);
        __builtin_amdgcn_s_setprio(0);

        // ---- iter boundary: drain tile t+1's loads (oldest 6 of 12) ----
        if (t < 14)       asm volatile("s_waitcnt vmcnt(6)" ::: "memory");
        else if (t == 14) asm volatile("s_waitcnt vmcnt(0)" ::: "memory");
        if (t < 15) __builtin_amdgcn_s_barrier();

        // rotate: read <- next, next <- stage, stage <- old read
        ushort* ta = rA; rA = nA; nA = sA; sA = ta;
        ushort* tb = rB; rB = nB; nB = sB; sB = tb;
    }

    // C layout: col = lane&15, row = (lane>>4)*4 + r  [m89/m91]
#pragma unroll
    for (int ni = 0; ni < 4; ni++) {
        int col = colBase + wcN + ni * 16 + l15;
        float bv = bias[col];
        float sc = (col < 2048) ? QK_SCALE : 1.0f;
        int bsel = col >> 10, cc = col & 1023;
        ushort* dst = (bsel == 0) ? out0 : ((bsel == 1) ? out1 : out2);
#pragma unroll
        for (int mi = 0; mi < 4; mi++) {
            f32x4 a = acc[mi][ni];
#pragma unroll
            for (int r = 0; r < 4; r++) {
                int row = rowBase + wrM + mi * 16 + q4 * 4 + r;
                dst[(size_t)row * 1024 + cc] = f2bf((a[r] + bv) * sc);
            }
        }
    }
}

// ---------------------------------------------------------------------------
// Out-proj GEMM: outf[M,1024] = A[M,1024] @ Bt[1024,1024]^T + bias + resid.
// 64x128 tile, BK=64, XOR-8 swizzle, grid (8,128)=1024 blocks, 24 KB LDS.
// (256,4) measured spill-free.
// ---------------------------------------------------------------------------
__global__ __launch_bounds__(256, 4) void gemm_out(
    const ushort* __restrict__ A, const ushort* __restrict__ Bt,
    const float* __restrict__ bias, const ushort* __restrict__ resid,
    float* __restrict__ outf) {
    const int K = 1024;
    __shared__ __align__(16) ushort As[64 * 64];    //  8 KB, 512 chunks
    __shared__ __align__(16) ushort Bs[128 * 64];   // 16 KB, 1024 chunks

    int tid = threadIdx.x;
    int lane = tid & 63, w = tid >> 6;
    int l15 = lane & 15, q4 = lane >> 4;
    int wr = (w >> 1) * 32, wc = (w & 1) * 64;
    int rowBase = blockIdx.y * 64, colBase = blockIdx.x * 128;

    const ushort* src[6]; ushort* dstp[6];
#pragma unroll
    for (int i = 0; i < 6; i++) {
        int id = i * 256 + w * 64 + lane;  // 0..1535
        if (id < 512) {
            int r = id >> 3, l = (id & 7) ^ ((id >> 3) & 7);
            src[i] = A + (size_t)(rowBase + r) * K + l * 8;
            dstp[i] = &As[id * 8];
        } else {
            int idb = id - 512;
            int r = idb >> 3, l = (idb & 7) ^ ((idb >> 3) & 7);
            src[i] = Bt + (size_t)(colBase + r) * K + l * 8;
            dstp[i] = &Bs[idb * 8];
        }
    }

    f32x4 acc[2][4];
    f32x4 zero = {0.f, 0.f, 0.f, 0.f};
#pragma unroll
    for (int mi = 0; mi < 2; mi++)
#pragma unroll
        for (int ni = 0; ni < 4; ni++) acc[mi][ni] = zero;

    for (int kt = 0; kt < 16; kt++) {
        __syncthreads();
#pragma unroll
        for (int i = 0; i < 6; i++) {
            gload_lds16(src[i], dstp[i]);
            src[i] += 64;
        }
        __syncthreads();

#pragma unroll
        for (int kk = 0; kk < 2; kk++) {
            short8 aF[2], bF[4];
#pragma unroll
            for (int mi = 0; mi < 2; mi++) {
                int r = wr + mi * 16 + l15;
                aF[mi] = *(const short8*)&As[r * 64 + ((kk * 4 + q4) ^ (r & 7)) * 8];
            }
#pragma unroll
            for (int ni = 0; ni < 4; ni++) {
                int r = wc + ni * 16 + l15;
                bF[ni] = *(const short8*)&Bs[r * 64 + ((kk * 4 + q4) ^ (r & 7)) * 8];
            }
#pragma unroll
            for (int mi = 0; mi < 2; mi++)
#pragma unroll
                for (int ni = 0; ni < 4; ni++)
                    acc[mi][ni] = __builtin_amdgcn_mfma_f32_16x16x32_bf16(
                        aF[mi], bF[ni], acc[mi][ni], 0, 0, 0);
        }
    }

#pragma unroll
    for (int ni = 0; ni < 4; ni++) {
        int col = colBase + wc + ni * 16 + l15;
        float bv = bias[col];
#pragma unroll
        for (int mi = 0; mi < 2; mi++) {
            f32x4 a = acc[mi][ni];
#pragma unroll
            for (int r = 0; r < 4; r++) {
                int row = rowBase + wr + mi * 16 + q4 * 4 + r;
                outf[(size_t)row * 1024 + col] =
                    a[r] + bv + bf2f(resid[(size_t)row * 1024 + col]);
            }
        }
    }
}

// ---------------------------------------------------------------------------
// Attention v7: one block = (head g, 128 q-rows); 8 waves x 16q; 512 thr.
// LDS 48 KB (Ks 16K + Vt 16K + Ps 16K).
//  - Ks [64 key][128 d], XOR-16 chunk swizzle, global_load_lds staged
//  - Vt [128 d][64 key], XOR-8 chunk swizzle, global_load_lds staged
//  - Ps [128 q][64 key], XOR-8 chunk swizzle, wave-private rows
// ---------------------------------------------------------------------------
__global__ __launch_bounds__(512) void attn_kernel(
    const ushort* __restrict__ qb, const ushort* __restrict__ kb,
    const ushort* __restrict__ vt, ushort* __restrict__ ob) {
    int g = blockIdx.x >> 3;       // head 0..63
    int qblk = blockIdx.x & 7;     // 128-row q block
    const ushort* Qh = qb + (size_t)g * 131072;
    const ushort* Kh = kb + (size_t)g * 131072;
    const ushort* Vh = vt + (size_t)g * 131072;  // [128 d][1024 key]

    __shared__ __align__(16) ushort Ks[64 * 128];   // 16 KB
    __shared__ __align__(16) ushort Vt[128 * 64];   // 16 KB
    __shared__ __align__(16) ushort Ps[128 * 64];   // 16 KB

    int tid = threadIdx.x, lane = tid & 63, w = tid >> 6;  // w in [0,8)
    int l15 = lane & 15, q4 = lane >> 4;
    int q0 = qblk * 128;

    // Q A-fragments: A[m=l15][k = ks*32 + q4*8 + j]
    short8 qf[4];
#pragma unroll
    for (int ks = 0; ks < 4; ks++)
        qf[ks] = *(const short8*)&Qh[(size_t)(q0 + w * 16 + l15) * 128 + ks * 32 + q4 * 8];

    f32x4 zero = {0.f, 0.f, 0.f, 0.f};
    f32x4 o[8];
#pragma unroll
    for (int ni = 0; ni < 8; ni++) o[ni] = zero;
    float plsum[4] = {0.f, 0.f, 0.f, 0.f};

    for (int kt = 0; kt < 16; kt++) {
        __syncthreads();
        // Ks: phys chunk p in key-row r holds logical chunk l = p ^ (r&15)
#pragma unroll
        for (int i = 0; i < 2; i++) {
            int linear = i * 512 + tid;          // 0..1023, wave-contiguous
            int r = linear >> 4, p = linear & 15;
            int l = p ^ (r & 15);
            gload_lds16(&Kh[(size_t)(kt * 64 + r) * 128 + l * 8], &Ks[linear * 8]);
        }
        // Vt: phys chunk p in d-row holds logical chunk c = p ^ (d&7)
#pragma unroll
        for (int i = 0; i < 2; i++) {
            int linear = i * 512 + tid;          // 0..1023
            int d = linear >> 3, p = linear & 7;
            int c = p ^ (d & 7);
            gload_lds16(&Vh[(size_t)d * 1024 + kt * 64 + c * 8], &Vt[linear * 8]);
        }
        __syncthreads();

        // S = Q K^T : 16q x 64key per wave
        f32x4 sacc[4];
#pragma unroll
        for (int ni = 0; ni < 4; ni++) sacc[ni] = zero;
#pragma unroll
        for (int ks = 0; ks < 4; ks++) {
#pragma unroll
            for (int ni = 0; ni < 4; ni++) {
                int r = ni * 16 + l15;
                int p = (ks * 4 + q4) ^ (r & 15);
                short8 bF = *(const short8*)&Ks[r * 128 + p * 8];
                sacc[ni] = __builtin_amdgcn_mfma_f32_16x16x32_bf16(
                    qf[ks], bF, sacc[ni], 0, 0, 0);
            }
        }

        // P = exp(S) -> Ps (swizzled); accumulate per-lane partial row sums
#pragma unroll
        for (int ni = 0; ni < 4; ni++) {
#pragma unroll
            for (int r = 0; r < 4; r++) {
                float pv = __expf(sacc[ni][r]);
                plsum[r] += pv;
                int qloc = w * 16 + q4 * 4 + r;       // wave-private rows
                int key = ni * 16 + l15;
                int pc = (key >> 3) ^ (qloc & 7);
                Ps[qloc * 64 + pc * 8 + (key & 7)] = f2bf(pv);
            }
        }

        // O += P V  (wave-private Ps rows; same-wave RAW handled by waitcnt)
#pragma unroll
        for (int ks2 = 0; ks2 < 2; ks2++) {
            int c = ks2 * 4 + q4;
            int row = w * 16 + l15;                   // row&7 == l15&7
            short8 aF = *(const short8*)&Ps[row * 64 + (c ^ (l15 & 7)) * 8];
#pragma unroll
            for (int ni = 0; ni < 8; ni++) {
                int d = ni * 16 + l15;
                short8 bF = *(const short8*)&Vt[d * 64 + (c ^ (d & 7)) * 8];
                o[ni] = __builtin_amdgcn_mfma_f32_16x16x32_bf16(aF, bF, o[ni], 0, 0, 0);
            }
        }
    }

    // row sums: reduce per-lane partials over the 16 l15-lanes
#pragma unroll
    for (int r = 0; r < 4; r++) {
#pragma unroll
        for (int m = 1; m < 16; m <<= 1) plsum[r] += __shfl_xor(plsum[r], m, 16);
    }
    float inv[4];
#pragma unroll
    for (int r = 0; r < 4; r++) inv[r] = 1.0f / plsum[r];
#pragma unroll
    for (int ni = 0; ni < 8; ni++)
#pragma unroll
        for (int r = 0; r < 4; r++) {
            int qrow = q0 + w * 16 + q4 * 4 + r;
            ob[(size_t)g * 131072 + (size_t)qrow * 128 + ni * 16 + l15] =
                f2bf(o[ni][r] * inv[r]);
        }
}

// ---------------------------------------------------------------------------
extern "C" void kernel_launch(void* const* d_in, const int* in_sizes, int n_in,
                              void* d_out, int out_size, void* d_ws, size_t ws_size,
                              hipStream_t stream) {
    const float* x     = (const float*)d_in[0];
    const float* ln_g  = (const float*)d_in[1];
    const float* ln_b  = (const float*)d_in[2];
    const float* w_qkv = (const float*)d_in[3];
    const float* b_qkv = (const float*)d_in[4];
    const float* w_out = (const float*)d_in[5];
    const float* b_out = (const float*)d_in[6];
    float* out = (float*)d_out;

    const size_t MC = 8192ull * 1024ull;  // 8.39M elems
    ushort* xn    = (ushort*)d_ws;
    ushort* wqkvT = xn + MC;
    ushort* woutT = wqkvT + 3072ull * 1024ull;
    ushort* qbuf  = woutT + 1024ull * 1024ull;
    ushort* kbuf  = qbuf + MC;
    ushort* vtbuf = kbuf + MC;        // V^T [64 heads][128 d][1024 seq]
    ushort* attnb = vtbuf + MC;       // scratch for raw V, then attn output
    // total: 46.14M ushorts = 92.3 MB (same layout as passing rounds 2-10)

    prep_kernel<<<6144, 256, 0, stream>>>(x, ln_g, ln_b, xn, w_qkv, wqkvT, w_out, woutT);
    // q,k -> qbuf,kbuf ; v -> attnb (scratch, row-major coalesced)
    gemm_qkv<<<768, 512, 0, stream>>>(xn, wqkvT, b_qkv, qbuf, kbuf, attnb);
    transpose_head<<<dim3(4, 32, 64), 256, 0, stream>>>(attnb, vtbuf);
    attn_kernel<<<512, 512, 0, stream>>>(qbuf, kbuf, vtbuf, attnb);
    gemm_out<<<dim3(8, 128), 256, 0, stream>>>(attnb, woutT, b_out, xn, out);
}

// Round 7
// 241.144 us; speedup vs baseline: 1.0287x; 1.0287x over previous
//
#include <hip/hip_runtime.h>
#include <hip/hip_bf16.h>

// ---------------------------------------------------------------------------
// AttentionBlock: B=8, L=1024, C=1024, H=8, ch=128.
// fp32 I/O, bf16 MFMA internal.
// R8 lesson: scattered 2B global stores amplify HBM writes ~10x.
// R9 lesson: launch_bounds floors past VGPR need -> scratch spills.
// R13 lesson: M-fast XCD swizzle -> 200MB fetch.  R14: M-band swizzle, 49MB.
// R15: 128x128 tile, 256 thr, 2-deep counted-vmcnt pipeline, 2 blocks/CU:
//      gemm_qkv 58.7us, 878 TF = 2-barrier structure ceiling.  KEEPER.
// R16 lesson: partial m201 phase port regressed (barrier cost, no benefit).
// R17 lesson (FAILED): fused V^T epilogue used the wrong reshape semantics.
//      Reference does RAW reshape [B,L,C]->[B*H,L,ch]: g=b*8+(l>>7),
//      s=(l&127)*8+(c>>7), d=c&127 -- heads interleave SEQ, not channels.
//      Under that mapping V^T has seq-stride-8 per block -> no coalesced
//      fused write exists.  transpose_head (flat-chunk transpose) is correct
//      by construction; keep it.
// R18: revert V to row-major scratch + transpose_head; KEEP the R17 gemm_out
//      2-deep port (inner loop byte-identical to proven gemm_qkv loop).
// ---------------------------------------------------------------------------

typedef __attribute__((ext_vector_type(8))) short short8;
typedef __attribute__((ext_vector_type(4))) float f32x4;

#define QK_SCALE 0.29730177875068026f  // 128^-0.25

__device__ __forceinline__ float bf2f(ushort u) {
    union { float f; unsigned int i; } c; c.i = ((unsigned int)u) << 16; return c.f;
}
__device__ __forceinline__ ushort f2bf(float f) {
    union { float f; unsigned int i; } c; c.f = f;
    unsigned int x = c.i;
    return (ushort)((x + 0x7FFFu + ((x >> 16) & 1u)) >> 16);  // RNE
}

// async 16B global->LDS (m97; LDS dest must be wave-uniform base + lane*16)
__device__ __forceinline__ void gload_lds16(const ushort* g, ushort* l) {
    __builtin_amdgcn_global_load_lds(
        (const __attribute__((address_space(1))) unsigned int*)g,
        (__attribute__((address_space(3))) unsigned int*)l, 16, 0, 0);
}

// ---------------------------------------------------------------------------
// Prep kernel: LN row-per-wave (blocks 0..2047, 4 rows/block, no barriers)
// + w_qkv transpose tiles (2048..5119) + w_out transpose (5120..6143).
// ---------------------------------------------------------------------------
__global__ __launch_bounds__(256) void prep_kernel(
    const float* __restrict__ x, const float* __restrict__ g,
    const float* __restrict__ b, ushort* __restrict__ xn,
    const float* __restrict__ w_qkv, ushort* __restrict__ wqkvT,
    const float* __restrict__ w_out, ushort* __restrict__ woutT) {
    __shared__ ushort t[32][33];
    int bid = blockIdx.x;
    int tid = threadIdx.x;
    if (bid < 2048) {
        // ---- LayerNorm: one row per wave ----
        int w = tid >> 6, lane = tid & 63;
        int row = bid * 4 + w;
        const float* xr = x + (size_t)row * 1024;
        float v[4][4];
        float s1 = 0.f, s2 = 0.f;
#pragma unroll
        for (int j = 0; j < 4; j++) {
            float4 t4 = *(const float4*)(xr + lane * 4 + j * 256);
            v[j][0] = t4.x; v[j][1] = t4.y; v[j][2] = t4.z; v[j][3] = t4.w;
#pragma unroll
            for (int e = 0; e < 4; e++) { s1 += v[j][e]; s2 += v[j][e] * v[j][e]; }
        }
#pragma unroll
        for (int m = 32; m >= 1; m >>= 1) { s1 += __shfl_xor(s1, m); s2 += __shfl_xor(s2, m); }
        float mu = s1 * (1.0f / 1024.0f);
        float var = s2 * (1.0f / 1024.0f) - mu * mu;
        float rs = rsqrtf(var + 1e-5f);
#pragma unroll
        for (int j = 0; j < 4; j++) {
            int c0 = lane * 4 + j * 256;
            float4 gg = *(const float4*)(g + c0);
            float4 bb = *(const float4*)(b + c0);
            float gA[4] = {gg.x, gg.y, gg.z, gg.w};
            float bA[4] = {bb.x, bb.y, bb.z, bb.w};
            ushort o[4];
#pragma unroll
            for (int e = 0; e < 4; e++) o[e] = f2bf((v[j][e] - mu) * rs * gA[e] + bA[e]);
            uint2 pk;
            pk.x = (uint)o[0] | ((uint)o[1] << 16);
            pk.y = (uint)o[2] | ((uint)o[3] << 16);
            *(uint2*)(xn + (size_t)row * 1024 + c0) = pk;
        }
    } else {
        // ---- weight transpose tile ----
        const float* in; ushort* out; int R, Cc, bx, by;
        if (bid < 5120) {
            int tt = bid - 2048;
            in = w_qkv; out = wqkvT; R = 1024; Cc = 3072;
            bx = (tt % 96) * 32; by = (tt / 96) * 32;
        } else {
            int tt = bid - 5120;
            in = w_out; out = woutT; R = 1024; Cc = 1024;
            bx = (tt % 32) * 32; by = (tt / 32) * 32;
        }
        int tx = tid & 31, ty = tid >> 5;
#pragma unroll
        for (int j = 0; j < 32; j += 8)
            t[ty + j][tx] = f2bf(in[(size_t)(by + ty + j) * Cc + bx + tx]);
        __syncthreads();
#pragma unroll
        for (int j = 0; j < 32; j += 8)
            out[(size_t)(bx + ty + j) * R + by + tx] = t[tx][ty + j];
    }
}

// ---------------------------------------------------------------------------
// Per-head bf16 transpose: in [64][1024][128] -> out [64][128][1024]
// (flat-chunk transpose == raw-reshape semantics; correct by construction)
// ---------------------------------------------------------------------------
__global__ __launch_bounds__(256) void transpose_head(
    const ushort* __restrict__ in, ushort* __restrict__ out) {
    __shared__ ushort t[32][33];
    int h = blockIdx.z;
    int j0 = blockIdx.y * 32;  // seq pos
    int d0 = blockIdx.x * 32;  // head dim
    int tx = threadIdx.x & 31, ty = threadIdx.x >> 5;
    const ushort* src = in + (size_t)h * 131072;
    ushort* dst = out + (size_t)h * 131072;
#pragma unroll
    for (int j = 0; j < 32; j += 8)
        t[ty + j][tx] = src[(size_t)(j0 + ty + j) * 128 + d0 + tx];
    __syncthreads();
#pragma unroll
    for (int j = 0; j < 32; j += 8)
        dst[(size_t)(d0 + ty + j) * 1024 + j0 + tx] = t[tx][ty + j];
}

// ---------------------------------------------------------------------------
// QKV GEMM R15 (proven): C[8192,3072] = A[8192,1024] @ Bt[3072,1024]^T.
// 128x128 tile, BK=64, 256 thr = 4 waves (2M x 2N, 64x64 per wave).
// LDS 64 KB -> 2 blocks/CU.  2-deep counted-vmcnt pipeline, vmcnt(8).
// XOR-8 chunk swizzle (conflict-free).  Grid 1536 = 2/CU x 3 waves.
// XCD x owns M-tiles [8x,8x+8) (2MB A band, L2-resident), N-fastest.
// ---------------------------------------------------------------------------
__device__ __forceinline__ void stage8(const ushort* __restrict__ Ab,
                                       const ushort* __restrict__ Bb, int t2,
                                       ushort* AsD, ushort* BsD, int tid) {
    const ushort* As_src = Ab + t2 * 64;
    const ushort* Bs_src = Bb + t2 * 64;
#pragma unroll
    for (int i = 0; i < 4; i++) {
        int lin = i * 256 + tid;             // 0..1023: 16B chunk id of A tile
        int r = lin >> 3, p = lin & 7;
        int l = p ^ (r & 7);                 // logical chunk at phys slot p
        gload_lds16(As_src + (size_t)r * 1024 + l * 8, &AsD[lin * 8]);
    }
#pragma unroll
    for (int i = 0; i < 4; i++) {
        int lin = i * 256 + tid;             // 0..1023: chunk id of B tile
        int r = lin >> 3, p = lin & 7;
        int l = p ^ (r & 7);
        gload_lds16(Bs_src + (size_t)r * 1024 + l * 8, &BsD[lin * 8]);
    }
}

__global__ __launch_bounds__(256, 2) void gemm_qkv(
    const ushort* __restrict__ A, const ushort* __restrict__ Bt,
    const float* __restrict__ bias, ushort* __restrict__ out0,
    ushort* __restrict__ out1, ushort* __restrict__ out2) {
    __shared__ __align__(16) ushort As[2][128 * 64];  // 32 KB
    __shared__ __align__(16) ushort Bs[2][128 * 64];  // 32 KB

    int tid = threadIdx.x;
    int lane = tid & 63, w = tid >> 6;       // 4 waves
    int l15 = lane & 15, q4 = lane >> 4;
    int wrM = (w >> 1) * 64;                 // wave M offset: 0/64
    int wcN = (w & 1) * 64;                  // wave N offset: 0/64

    int bid = blockIdx.x;
    int xcd = bid & 7;
    int i = bid >> 3;                        // 0..191
    int by = xcd * 8 + (i & 7);              // M-tile 0..63
    int bx = i >> 3;                         // N-tile 0..23
    int rowBase = by * 128, colBase = bx * 128;

    const ushort* Ab = A + (size_t)rowBase * 1024;
    const ushort* Bb = Bt + (size_t)colBase * 1024;

    f32x4 acc[4][4];
    f32x4 zero = {0.f, 0.f, 0.f, 0.f};
#pragma unroll
    for (int mi = 0; mi < 4; mi++)
#pragma unroll
        for (int ni = 0; ni < 4; ni++) acc[mi][ni] = zero;

    // prologue: fill both buffers, wait only for buf0 (K1 stays in flight)
    stage8(Ab, Bb, 0, &As[0][0], &Bs[0][0], tid);
    stage8(Ab, Bb, 1, &As[1][0], &Bs[1][0], tid);
    asm volatile("s_waitcnt vmcnt(8)" ::: "memory");
    __builtin_amdgcn_s_barrier();

    for (int t = 0; t < 16; ++t) {
        const int cur = t & 1;
        const ushort* Ac = &As[cur][0];
        const ushort* Bc = &Bs[cur][0];

        // ---- read all 16 fragments of this K-tile into registers ----
        short8 aF[4][2], bF[4][2];
#pragma unroll
        for (int kk = 0; kk < 2; kk++) {
#pragma unroll
            for (int mi = 0; mi < 4; mi++) {
                int r = wrM + mi * 16 + l15;
                aF[mi][kk] = *(const short8*)&Ac[r * 64 + ((kk * 4 + q4) ^ (r & 7)) * 8];
            }
#pragma unroll
            for (int ni = 0; ni < 4; ni++) {
                int r = wcN + ni * 16 + l15;
                bF[ni][kk] = *(const short8*)&Bc[r * 64 + ((kk * 4 + q4) ^ (r & 7)) * 8];
            }
        }

        // ---- MFMA kk=0 ----
        __builtin_amdgcn_s_setprio(1);
#pragma unroll
        for (int mi = 0; mi < 4; mi++)
#pragma unroll
            for (int ni = 0; ni < 4; ni++)
                acc[mi][ni] = __builtin_amdgcn_mfma_f32_16x16x32_bf16(
                    aF[mi][0], bF[ni][0], acc[mi][ni], 0, 0, 0);
        __builtin_amdgcn_s_setprio(0);

        // all 16 reads sampled -> buf[cur] free for restaging (block-wide)
        asm volatile("s_waitcnt lgkmcnt(0)" ::: "memory");
        __builtin_amdgcn_s_barrier();
        if (t < 14) stage8(Ab, Bb, t + 2, &As[cur][0], &Bs[cur][0], tid);

        // ---- MFMA kk=1 (hides the stage issue + in-flight loads) ----
        __builtin_amdgcn_s_setprio(1);
#pragma unroll
        for (int mi = 0; mi < 4; mi++)
#pragma unroll
            for (int ni = 0; ni < 4; ni++)
                acc[mi][ni] = __builtin_amdgcn_mfma_f32_16x16x32_bf16(
                    aF[mi][1], bF[ni][1], acc[mi][ni], 0, 0, 0);
        __builtin_amdgcn_s_setprio(0);

        if (t < 15) {
            if (t < 14) asm volatile("s_waitcnt vmcnt(8)" ::: "memory");
            else        asm volatile("s_waitcnt vmcnt(0)" ::: "memory");
            __builtin_amdgcn_s_barrier();
        }
    }

    // C layout: col = lane&15, row = (lane>>4)*4 + r  [m89/m91]
#pragma unroll
    for (int ni = 0; ni < 4; ni++) {
        int col = colBase + wcN + ni * 16 + l15;
        float bv = bias[col];
        float sc = (col < 2048) ? QK_SCALE : 1.0f;
        int bsel = col >> 10, cc = col & 1023;
        ushort* dst = (bsel == 0) ? out0 : ((bsel == 1) ? out1 : out2);
#pragma unroll
        for (int mi = 0; mi < 4; mi++) {
            f32x4 a = acc[mi][ni];
#pragma unroll
            for (int r = 0; r < 4; r++) {
                int row = rowBase + wrM + mi * 16 + q4 * 4 + r;
                dst[(size_t)row * 1024 + cc] = f2bf((a[r] + bv) * sc);
            }
        }
    }
}

// ---------------------------------------------------------------------------
// Out-proj GEMM R18: outf[8192,1024] = A @ woutT^T + bias + resid (fp32 out).
// R15 2-deep structure ported verbatim: 128x128 tile, 256 thr, 64KB LDS,
// vmcnt(8) counted pipeline, XOR-8 swizzle.  Grid 512 = exactly 2/CU.
// XCD x owns M-tiles [8x,8x+8) (2MB A band), N-fastest (8 N-tiles).
// ---------------------------------------------------------------------------
__global__ __launch_bounds__(256, 2) void gemm_out(
    const ushort* __restrict__ A, const ushort* __restrict__ Bt,
    const float* __restrict__ bias, const ushort* __restrict__ resid,
    float* __restrict__ outf) {
    __shared__ __align__(16) ushort As[2][128 * 64];  // 32 KB
    __shared__ __align__(16) ushort Bs[2][128 * 64];  // 32 KB

    int tid = threadIdx.x;
    int lane = tid & 63, w = tid >> 6;       // 4 waves
    int l15 = lane & 15, q4 = lane >> 4;
    int wrM = (w >> 1) * 64;
    int wcN = (w & 1) * 64;

    int bid = blockIdx.x;
    int xcd = bid & 7;
    int i = bid >> 3;                        // 0..63
    int by = xcd * 8 + (i & 7);              // M-tile 0..63
    int bx = i >> 3;                         // N-tile 0..7
    int rowBase = by * 128, colBase = bx * 128;

    const ushort* Ab = A + (size_t)rowBase * 1024;
    const ushort* Bb = Bt + (size_t)colBase * 1024;

    f32x4 acc[4][4];
    f32x4 zero = {0.f, 0.f, 0.f, 0.f};
#pragma unroll
    for (int mi = 0; mi < 4; mi++)
#pragma unroll
        for (int ni = 0; ni < 4; ni++) acc[mi][ni] = zero;

    stage8(Ab, Bb, 0, &As[0][0], &Bs[0][0], tid);
    stage8(Ab, Bb, 1, &As[1][0], &Bs[1][0], tid);
    asm volatile("s_waitcnt vmcnt(8)" ::: "memory");
    __builtin_amdgcn_s_barrier();

    for (int t = 0; t < 16; ++t) {
        const int cur = t & 1;
        const ushort* Ac = &As[cur][0];
        const ushort* Bc = &Bs[cur][0];

        short8 aF[4][2], bF[4][2];
#pragma unroll
        for (int kk = 0; kk < 2; kk++) {
#pragma unroll
            for (int mi = 0; mi < 4; mi++) {
                int r = wrM + mi * 16 + l15;
                aF[mi][kk] = *(const short8*)&Ac[r * 64 + ((kk * 4 + q4) ^ (r & 7)) * 8];
            }
#pragma unroll
            for (int ni = 0; ni < 4; ni++) {
                int r = wcN + ni * 16 + l15;
                bF[ni][kk] = *(const short8*)&Bc[r * 64 + ((kk * 4 + q4) ^ (r & 7)) * 8];
            }
        }

        __builtin_amdgcn_s_setprio(1);
#pragma unroll
        for (int mi = 0; mi < 4; mi++)
#pragma unroll
            for (int ni = 0; ni < 4; ni++)
                acc[mi][ni] = __builtin_amdgcn_mfma_f32_16x16x32_bf16(
                    aF[mi][0], bF[ni][0], acc[mi][ni], 0, 0, 0);
        __builtin_amdgcn_s_setprio(0);

        asm volatile("s_waitcnt lgkmcnt(0)" ::: "memory");
        __builtin_amdgcn_s_barrier();
        if (t < 14) stage8(Ab, Bb, t + 2, &As[cur][0], &Bs[cur][0], tid);

        __builtin_amdgcn_s_setprio(1);
#pragma unroll
        for (int mi = 0; mi < 4; mi++)
#pragma unroll
            for (int ni = 0; ni < 4; ni++)
                acc[mi][ni] = __builtin_amdgcn_mfma_f32_16x16x32_bf16(
                    aF[mi][1], bF[ni][1], acc[mi][ni], 0, 0, 0);
        __builtin_amdgcn_s_setprio(0);

        if (t < 15) {
            if (t < 14) asm volatile("s_waitcnt vmcnt(8)" ::: "memory");
            else        asm volatile("s_waitcnt vmcnt(0)" ::: "memory");
            __builtin_amdgcn_s_barrier();
        }
    }

#pragma unroll
    for (int ni = 0; ni < 4; ni++) {
        int col = colBase + wcN + ni * 16 + l15;
        float bv = bias[col];
#pragma unroll
        for (int mi = 0; mi < 4; mi++) {
            f32x4 a = acc[mi][ni];
#pragma unroll
            for (int r = 0; r < 4; r++) {
                int row = rowBase + wrM + mi * 16 + q4 * 4 + r;
                outf[(size_t)row * 1024 + col] =
                    a[r] + bv + bf2f(resid[(size_t)row * 1024 + col]);
            }
        }
    }
}

// ---------------------------------------------------------------------------
// Attention v7: one block = (head g, 128 q-rows); 8 waves x 16q; 512 thr.
// LDS 48 KB (Ks 16K + Vt 16K + Ps 16K).
//  - Ks [64 key][128 d], XOR-16 chunk swizzle, global_load_lds staged
//  - Vt [128 d][64 key], XOR-8 chunk swizzle, global_load_lds staged
//  - Ps [128 q][64 key], XOR-8 chunk swizzle, wave-private rows
// ---------------------------------------------------------------------------
__global__ __launch_bounds__(512) void attn_kernel(
    const ushort* __restrict__ qb, const ushort* __restrict__ kb,
    const ushort* __restrict__ vt, ushort* __restrict__ ob) {
    int g = blockIdx.x >> 3;       // head 0..63
    int qblk = blockIdx.x & 7;     // 128-row q block
    const ushort* Qh = qb + (size_t)g * 131072;
    const ushort* Kh = kb + (size_t)g * 131072;
    const ushort* Vh = vt + (size_t)g * 131072;  // [128 d][1024 key]

    __shared__ __align__(16) ushort Ks[64 * 128];   // 16 KB
    __shared__ __align__(16) ushort Vt[128 * 64];   // 16 KB
    __shared__ __align__(16) ushort Ps[128 * 64];   // 16 KB

    int tid = threadIdx.x, lane = tid & 63, w = tid >> 6;  // w in [0,8)
    int l15 = lane & 15, q4 = lane >> 4;
    int q0 = qblk * 128;

    // Q A-fragments: A[m=l15][k = ks*32 + q4*8 + j]
    short8 qf[4];
#pragma unroll
    for (int ks = 0; ks < 4; ks++)
        qf[ks] = *(const short8*)&Qh[(size_t)(q0 + w * 16 + l15) * 128 + ks * 32 + q4 * 8];

    f32x4 zero = {0.f, 0.f, 0.f, 0.f};
    f32x4 o[8];
#pragma unroll
    for (int ni = 0; ni < 8; ni++) o[ni] = zero;
    float plsum[4] = {0.f, 0.f, 0.f, 0.f};

    for (int kt = 0; kt < 16; kt++) {
        __syncthreads();
        // Ks: phys chunk p in key-row r holds logical chunk l = p ^ (r&15)
#pragma unroll
        for (int i = 0; i < 2; i++) {
            int linear = i * 512 + tid;          // 0..1023, wave-contiguous
            int r = linear >> 4, p = linear & 15;
            int l = p ^ (r & 15);
            gload_lds16(&Kh[(size_t)(kt * 64 + r) * 128 + l * 8], &Ks[linear * 8]);
        }
        // Vt: phys chunk p in d-row holds logical chunk c = p ^ (d&7)
#pragma unroll
        for (int i = 0; i < 2; i++) {
            int linear = i * 512 + tid;          // 0..1023
            int d = linear >> 3, p = linear & 7;
            int c = p ^ (d & 7);
            gload_lds16(&Vh[(size_t)d * 1024 + kt * 64 + c * 8], &Vt[linear * 8]);
        }
        __syncthreads();

        // S = Q K^T : 16q x 64key per wave
        f32x4 sacc[4];
#pragma unroll
        for (int ni = 0; ni < 4; ni++) sacc[ni] = zero;
#pragma unroll
        for (int ks = 0; ks < 4; ks++) {
#pragma unroll
            for (int ni = 0; ni < 4; ni++) {
                int r = ni * 16 + l15;
                int p = (ks * 4 + q4) ^ (r & 15);
                short8 bF = *(const short8*)&Ks[r * 128 + p * 8];
                sacc[ni] = __builtin_amdgcn_mfma_f32_16x16x32_bf16(
                    qf[ks], bF, sacc[ni], 0, 0, 0);
            }
        }

        // P = exp(S) -> Ps (swizzled); accumulate per-lane partial row sums
#pragma unroll
        for (int ni = 0; ni < 4; ni++) {
#pragma unroll
            for (int r = 0; r < 4; r++) {
                float pv = __expf(sacc[ni][r]);
                plsum[r] += pv;
                int qloc = w * 16 + q4 * 4 + r;       // wave-private rows
                int key = ni * 16 + l15;
                int pc = (key >> 3) ^ (qloc & 7);
                Ps[qloc * 64 + pc * 8 + (key & 7)] = f2bf(pv);
            }
        }

        // O += P V  (wave-private Ps rows; same-wave RAW handled by waitcnt)
#pragma unroll
        for (int ks2 = 0; ks2 < 2; ks2++) {
            int c = ks2 * 4 + q4;
            int row = w * 16 + l15;                   // row&7 == l15&7
            short8 aF = *(const short8*)&Ps[row * 64 + (c ^ (l15 & 7)) * 8];
#pragma unroll
            for (int ni = 0; ni < 8; ni++) {
                int d = ni * 16 + l15;
                short8 bF = *(const short8*)&Vt[d * 64 + (c ^ (d & 7)) * 8];
                o[ni] = __builtin_amdgcn_mfma_f32_16x16x32_bf16(aF, bF, o[ni], 0, 0, 0);
            }
        }
    }

    // row sums: reduce per-lane partials over the 16 l15-lanes
#pragma unroll
    for (int r = 0; r < 4; r++) {
#pragma unroll
        for (int m = 1; m < 16; m <<= 1) plsum[r] += __shfl_xor(plsum[r], m, 16);
    }
    float inv[4];
#pragma unroll
    for (int r = 0; r < 4; r++) inv[r] = 1.0f / plsum[r];
#pragma unroll
    for (int ni = 0; ni < 8; ni++)
#pragma unroll
        for (int r = 0; r < 4; r++) {
            int qrow = q0 + w * 16 + q4 * 4 + r;
            ob[(size_t)g * 131072 + (size_t)qrow * 128 + ni * 16 + l15] =
                f2bf(o[ni][r] * inv[r]);
        }
}

// ---------------------------------------------------------------------------
extern "C" void kernel_launch(void* const* d_in, const int* in_sizes, int n_in,
                              void* d_out, int out_size, void* d_ws, size_t ws_size,
                              hipStream_t stream) {
    const float* x     = (const float*)d_in[0];
    const float* ln_g  = (const float*)d_in[1];
    const float* ln_b  = (const float*)d_in[2];
    const float* w_qkv = (const float*)d_in[3];
    const float* b_qkv = (const float*)d_in[4];
    const float* w_out = (const float*)d_in[5];
    const float* b_out = (const float*)d_in[6];
    float* out = (float*)d_out;

    const size_t MC = 8192ull * 1024ull;  // 8.39M elems
    ushort* xn    = (ushort*)d_ws;
    ushort* wqkvT = xn + MC;
    ushort* woutT = wqkvT + 3072ull * 1024ull;
    ushort* qbuf  = woutT + 1024ull * 1024ull;
    ushort* kbuf  = qbuf + MC;
    ushort* vtbuf = kbuf + MC;        // V^T [64 heads][128 d][1024 seq]
    ushort* attnb = vtbuf + MC;       // scratch for raw V, then attn output
    // total: 46.14M ushorts = 92.3 MB (same layout as passing rounds 2-10)

    prep_kernel<<<6144, 256, 0, stream>>>(x, ln_g, ln_b, xn, w_qkv, wqkvT, w_out, woutT);
    // q,k -> qbuf,kbuf ; v -> attnb (scratch, row-major coalesced)
    gemm_qkv<<<1536, 256, 0, stream>>>(xn, wqkvT, b_qkv, qbuf, kbuf, attnb);
    transpose_head<<<dim3(4, 32, 64), 256, 0, stream>>>(attnb, vtbuf);
    attn_kernel<<<512, 512, 0, stream>>>(qbuf, kbuf, vtbuf, attnb);
    gemm_out<<<512, 256, 0, stream>>>(attnb, woutT, b_out, xn, out);
}

// Round 8
// 238.978 us; speedup vs baseline: 1.0381x; 1.0091x over previous
//
#include <hip/hip_runtime.h>
#include <hip/hip_bf16.h>

// ---------------------------------------------------------------------------
// AttentionBlock: B=8, L=1024, C=1024, H=8, ch=128.
// fp32 I/O, bf16 MFMA internal.
// R8: scattered 2B global stores amplify HBM writes ~10x.
// R9: launch_bounds floors past VGPR need -> scratch spills.
// R13/R14: XCD M-band swizzle (2MB band L2-resident) -> 49MB fetch.
// R15: 128x128 tile, 2-deep counted-vmcnt pipeline -> gemm_qkv 58.7us,
//      878 TF = 2-barrier structure ceiling.  KEEPER.
// R16: partial m201 phase port regressed (barrier cost without benefit).
// R17: fused V^T epilogue FAILED -- raw reshape interleaves SEQ not channels;
//      transpose_head is correct by construction.  gemm_out 2-deep port OK.
// R18: 241.1us.  attn_kernel is the last 0-deep-drain kernel (~34.4 GFLOP,
//      est <= 58us).  R19: apply R15 recipe to attn: double-buffered K/V
//      (80KB LDS), counted vmcnt(4), setprio on MFMA clusters, XCD
//      head-grouping swizzle (per-XCD K/V working set 32MB -> 4MB).
// ---------------------------------------------------------------------------

typedef __attribute__((ext_vector_type(8))) short short8;
typedef __attribute__((ext_vector_type(4))) float f32x4;

#define QK_SCALE 0.29730177875068026f  // 128^-0.25

__device__ __forceinline__ float bf2f(ushort u) {
    union { float f; unsigned int i; } c; c.i = ((unsigned int)u) << 16; return c.f;
}
__device__ __forceinline__ ushort f2bf(float f) {
    union { float f; unsigned int i; } c; c.f = f;
    unsigned int x = c.i;
    return (ushort)((x + 0x7FFFu + ((x >> 16) & 1u)) >> 16);  // RNE
}

// async 16B global->LDS (m97; LDS dest must be wave-uniform base + lane*16)
__device__ __forceinline__ void gload_lds16(const ushort* g, ushort* l) {
    __builtin_amdgcn_global_load_lds(
        (const __attribute__((address_space(1))) unsigned int*)g,
        (__attribute__((address_space(3))) unsigned int*)l, 16, 0, 0);
}

// ---------------------------------------------------------------------------
// Prep kernel: LN row-per-wave (blocks 0..2047, 4 rows/block, no barriers)
// + w_qkv transpose tiles (2048..5119) + w_out transpose (5120..6143).
// ---------------------------------------------------------------------------
__global__ __launch_bounds__(256) void prep_kernel(
    const float* __restrict__ x, const float* __restrict__ g,
    const float* __restrict__ b, ushort* __restrict__ xn,
    const float* __restrict__ w_qkv, ushort* __restrict__ wqkvT,
    const float* __restrict__ w_out, ushort* __restrict__ woutT) {
    __shared__ ushort t[32][33];
    int bid = blockIdx.x;
    int tid = threadIdx.x;
    if (bid < 2048) {
        // ---- LayerNorm: one row per wave ----
        int w = tid >> 6, lane = tid & 63;
        int row = bid * 4 + w;
        const float* xr = x + (size_t)row * 1024;
        float v[4][4];
        float s1 = 0.f, s2 = 0.f;
#pragma unroll
        for (int j = 0; j < 4; j++) {
            float4 t4 = *(const float4*)(xr + lane * 4 + j * 256);
            v[j][0] = t4.x; v[j][1] = t4.y; v[j][2] = t4.z; v[j][3] = t4.w;
#pragma unroll
            for (int e = 0; e < 4; e++) { s1 += v[j][e]; s2 += v[j][e] * v[j][e]; }
        }
#pragma unroll
        for (int m = 32; m >= 1; m >>= 1) { s1 += __shfl_xor(s1, m); s2 += __shfl_xor(s2, m); }
        float mu = s1 * (1.0f / 1024.0f);
        float var = s2 * (1.0f / 1024.0f) - mu * mu;
        float rs = rsqrtf(var + 1e-5f);
#pragma unroll
        for (int j = 0; j < 4; j++) {
            int c0 = lane * 4 + j * 256;
            float4 gg = *(const float4*)(g + c0);
            float4 bb = *(const float4*)(b + c0);
            float gA[4] = {gg.x, gg.y, gg.z, gg.w};
            float bA[4] = {bb.x, bb.y, bb.z, bb.w};
            ushort o[4];
#pragma unroll
            for (int e = 0; e < 4; e++) o[e] = f2bf((v[j][e] - mu) * rs * gA[e] + bA[e]);
            uint2 pk;
            pk.x = (uint)o[0] | ((uint)o[1] << 16);
            pk.y = (uint)o[2] | ((uint)o[3] << 16);
            *(uint2*)(xn + (size_t)row * 1024 + c0) = pk;
        }
    } else {
        // ---- weight transpose tile ----
        const float* in; ushort* out; int R, Cc, bx, by;
        if (bid < 5120) {
            int tt = bid - 2048;
            in = w_qkv; out = wqkvT; R = 1024; Cc = 3072;
            bx = (tt % 96) * 32; by = (tt / 96) * 32;
        } else {
            int tt = bid - 5120;
            in = w_out; out = woutT; R = 1024; Cc = 1024;
            bx = (tt % 32) * 32; by = (tt / 32) * 32;
        }
        int tx = tid & 31, ty = tid >> 5;
#pragma unroll
        for (int j = 0; j < 32; j += 8)
            t[ty + j][tx] = f2bf(in[(size_t)(by + ty + j) * Cc + bx + tx]);
        __syncthreads();
#pragma unroll
        for (int j = 0; j < 32; j += 8)
            out[(size_t)(bx + ty + j) * R + by + tx] = t[tx][ty + j];
    }
}

// ---------------------------------------------------------------------------
// Per-head bf16 transpose: in [64][1024][128] -> out [64][128][1024]
// (flat-chunk transpose == raw-reshape semantics; correct by construction)
// ---------------------------------------------------------------------------
__global__ __launch_bounds__(256) void transpose_head(
    const ushort* __restrict__ in, ushort* __restrict__ out) {
    __shared__ ushort t[32][33];
    int h = blockIdx.z;
    int j0 = blockIdx.y * 32;  // seq pos
    int d0 = blockIdx.x * 32;  // head dim
    int tx = threadIdx.x & 31, ty = threadIdx.x >> 5;
    const ushort* src = in + (size_t)h * 131072;
    ushort* dst = out + (size_t)h * 131072;
#pragma unroll
    for (int j = 0; j < 32; j += 8)
        t[ty + j][tx] = src[(size_t)(j0 + ty + j) * 128 + d0 + tx];
    __syncthreads();
#pragma unroll
    for (int j = 0; j < 32; j += 8)
        dst[(size_t)(d0 + ty + j) * 1024 + j0 + tx] = t[tx][ty + j];
}

// ---------------------------------------------------------------------------
// QKV GEMM R15 (proven): C[8192,3072] = A[8192,1024] @ Bt[3072,1024]^T.
// 128x128 tile, BK=64, 256 thr = 4 waves.  LDS 64 KB -> 2 blocks/CU.
// 2-deep counted-vmcnt pipeline, vmcnt(8).  XOR-8 swizzle (conflict-free).
// Grid 1536 = 2/CU x 3 waves.  XCD x owns M-tiles [8x,8x+8), N-fastest.
// ---------------------------------------------------------------------------
__device__ __forceinline__ void stage8(const ushort* __restrict__ Ab,
                                       const ushort* __restrict__ Bb, int t2,
                                       ushort* AsD, ushort* BsD, int tid) {
    const ushort* As_src = Ab + t2 * 64;
    const ushort* Bs_src = Bb + t2 * 64;
#pragma unroll
    for (int i = 0; i < 4; i++) {
        int lin = i * 256 + tid;             // 0..1023: 16B chunk id of A tile
        int r = lin >> 3, p = lin & 7;
        int l = p ^ (r & 7);                 // logical chunk at phys slot p
        gload_lds16(As_src + (size_t)r * 1024 + l * 8, &AsD[lin * 8]);
    }
#pragma unroll
    for (int i = 0; i < 4; i++) {
        int lin = i * 256 + tid;             // 0..1023: chunk id of B tile
        int r = lin >> 3, p = lin & 7;
        int l = p ^ (r & 7);
        gload_lds16(Bs_src + (size_t)r * 1024 + l * 8, &BsD[lin * 8]);
    }
}

__global__ __launch_bounds__(256, 2) void gemm_qkv(
    const ushort* __restrict__ A, const ushort* __restrict__ Bt,
    const float* __restrict__ bias, ushort* __restrict__ out0,
    ushort* __restrict__ out1, ushort* __restrict__ out2) {
    __shared__ __align__(16) ushort As[2][128 * 64];  // 32 KB
    __shared__ __align__(16) ushort Bs[2][128 * 64];  // 32 KB

    int tid = threadIdx.x;
    int lane = tid & 63, w = tid >> 6;       // 4 waves
    int l15 = lane & 15, q4 = lane >> 4;
    int wrM = (w >> 1) * 64;                 // wave M offset: 0/64
    int wcN = (w & 1) * 64;                  // wave N offset: 0/64

    int bid = blockIdx.x;
    int xcd = bid & 7;
    int i = bid >> 3;                        // 0..191
    int by = xcd * 8 + (i & 7);              // M-tile 0..63
    int bx = i >> 3;                         // N-tile 0..23
    int rowBase = by * 128, colBase = bx * 128;

    const ushort* Ab = A + (size_t)rowBase * 1024;
    const ushort* Bb = Bt + (size_t)colBase * 1024;

    f32x4 acc[4][4];
    f32x4 zero = {0.f, 0.f, 0.f, 0.f};
#pragma unroll
    for (int mi = 0; mi < 4; mi++)
#pragma unroll
        for (int ni = 0; ni < 4; ni++) acc[mi][ni] = zero;

    // prologue: fill both buffers, wait only for buf0 (K1 stays in flight)
    stage8(Ab, Bb, 0, &As[0][0], &Bs[0][0], tid);
    stage8(Ab, Bb, 1, &As[1][0], &Bs[1][0], tid);
    asm volatile("s_waitcnt vmcnt(8)" ::: "memory");
    __builtin_amdgcn_s_barrier();

    for (int t = 0; t < 16; ++t) {
        const int cur = t & 1;
        const ushort* Ac = &As[cur][0];
        const ushort* Bc = &Bs[cur][0];

        // ---- read all 16 fragments of this K-tile into registers ----
        short8 aF[4][2], bF[4][2];
#pragma unroll
        for (int kk = 0; kk < 2; kk++) {
#pragma unroll
            for (int mi = 0; mi < 4; mi++) {
                int r = wrM + mi * 16 + l15;
                aF[mi][kk] = *(const short8*)&Ac[r * 64 + ((kk * 4 + q4) ^ (r & 7)) * 8];
            }
#pragma unroll
            for (int ni = 0; ni < 4; ni++) {
                int r = wcN + ni * 16 + l15;
                bF[ni][kk] = *(const short8*)&Bc[r * 64 + ((kk * 4 + q4) ^ (r & 7)) * 8];
            }
        }

        // ---- MFMA kk=0 ----
        __builtin_amdgcn_s_setprio(1);
#pragma unroll
        for (int mi = 0; mi < 4; mi++)
#pragma unroll
            for (int ni = 0; ni < 4; ni++)
                acc[mi][ni] = __builtin_amdgcn_mfma_f32_16x16x32_bf16(
                    aF[mi][0], bF[ni][0], acc[mi][ni], 0, 0, 0);
        __builtin_amdgcn_s_setprio(0);

        // all 16 reads sampled -> buf[cur] free for restaging (block-wide)
        asm volatile("s_waitcnt lgkmcnt(0)" ::: "memory");
        __builtin_amdgcn_s_barrier();
        if (t < 14) stage8(Ab, Bb, t + 2, &As[cur][0], &Bs[cur][0], tid);

        // ---- MFMA kk=1 (hides the stage issue + in-flight loads) ----
        __builtin_amdgcn_s_setprio(1);
#pragma unroll
        for (int mi = 0; mi < 4; mi++)
#pragma unroll
            for (int ni = 0; ni < 4; ni++)
                acc[mi][ni] = __builtin_amdgcn_mfma_f32_16x16x32_bf16(
                    aF[mi][1], bF[ni][1], acc[mi][ni], 0, 0, 0);
        __builtin_amdgcn_s_setprio(0);

        if (t < 15) {
            if (t < 14) asm volatile("s_waitcnt vmcnt(8)" ::: "memory");
            else        asm volatile("s_waitcnt vmcnt(0)" ::: "memory");
            __builtin_amdgcn_s_barrier();
        }
    }

    // C layout: col = lane&15, row = (lane>>4)*4 + r  [m89/m91]
#pragma unroll
    for (int ni = 0; ni < 4; ni++) {
        int col = colBase + wcN + ni * 16 + l15;
        float bv = bias[col];
        float sc = (col < 2048) ? QK_SCALE : 1.0f;
        int bsel = col >> 10, cc = col & 1023;
        ushort* dst = (bsel == 0) ? out0 : ((bsel == 1) ? out1 : out2);
#pragma unroll
        for (int mi = 0; mi < 4; mi++) {
            f32x4 a = acc[mi][ni];
#pragma unroll
            for (int r = 0; r < 4; r++) {
                int row = rowBase + wrM + mi * 16 + q4 * 4 + r;
                dst[(size_t)row * 1024 + cc] = f2bf((a[r] + bv) * sc);
            }
        }
    }
}

// ---------------------------------------------------------------------------
// Out-proj GEMM R18: outf[8192,1024] = A @ woutT^T + bias + resid (fp32 out).
// R15 2-deep structure: 128x128 tile, 256 thr, 64KB LDS, vmcnt(8) pipeline.
// Grid 512 = exactly 2/CU.  XCD x owns M-tiles [8x,8x+8), N-fastest.
// ---------------------------------------------------------------------------
__global__ __launch_bounds__(256, 2) void gemm_out(
    const ushort* __restrict__ A, const ushort* __restrict__ Bt,
    const float* __restrict__ bias, const ushort* __restrict__ resid,
    float* __restrict__ outf) {
    __shared__ __align__(16) ushort As[2][128 * 64];  // 32 KB
    __shared__ __align__(16) ushort Bs[2][128 * 64];  // 32 KB

    int tid = threadIdx.x;
    int lane = tid & 63, w = tid >> 6;       // 4 waves
    int l15 = lane & 15, q4 = lane >> 4;
    int wrM = (w >> 1) * 64;
    int wcN = (w & 1) * 64;

    int bid = blockIdx.x;
    int xcd = bid & 7;
    int i = bid >> 3;                        // 0..63
    int by = xcd * 8 + (i & 7);              // M-tile 0..63
    int bx = i >> 3;                         // N-tile 0..7
    int rowBase = by * 128, colBase = bx * 128;

    const ushort* Ab = A + (size_t)rowBase * 1024;
    const ushort* Bb = Bt + (size_t)colBase * 1024;

    f32x4 acc[4][4];
    f32x4 zero = {0.f, 0.f, 0.f, 0.f};
#pragma unroll
    for (int mi = 0; mi < 4; mi++)
#pragma unroll
        for (int ni = 0; ni < 4; ni++) acc[mi][ni] = zero;

    stage8(Ab, Bb, 0, &As[0][0], &Bs[0][0], tid);
    stage8(Ab, Bb, 1, &As[1][0], &Bs[1][0], tid);
    asm volatile("s_waitcnt vmcnt(8)" ::: "memory");
    __builtin_amdgcn_s_barrier();

    for (int t = 0; t < 16; ++t) {
        const int cur = t & 1;
        const ushort* Ac = &As[cur][0];
        const ushort* Bc = &Bs[cur][0];

        short8 aF[4][2], bF[4][2];
#pragma unroll
        for (int kk = 0; kk < 2; kk++) {
#pragma unroll
            for (int mi = 0; mi < 4; mi++) {
                int r = wrM + mi * 16 + l15;
                aF[mi][kk] = *(const short8*)&Ac[r * 64 + ((kk * 4 + q4) ^ (r & 7)) * 8];
            }
#pragma unroll
            for (int ni = 0; ni < 4; ni++) {
                int r = wcN + ni * 16 + l15;
                bF[ni][kk] = *(const short8*)&Bc[r * 64 + ((kk * 4 + q4) ^ (r & 7)) * 8];
            }
        }

        __builtin_amdgcn_s_setprio(1);
#pragma unroll
        for (int mi = 0; mi < 4; mi++)
#pragma unroll
            for (int ni = 0; ni < 4; ni++)
                acc[mi][ni] = __builtin_amdgcn_mfma_f32_16x16x32_bf16(
                    aF[mi][0], bF[ni][0], acc[mi][ni], 0, 0, 0);
        __builtin_amdgcn_s_setprio(0);

        asm volatile("s_waitcnt lgkmcnt(0)" ::: "memory");
        __builtin_amdgcn_s_barrier();
        if (t < 14) stage8(Ab, Bb, t + 2, &As[cur][0], &Bs[cur][0], tid);

        __builtin_amdgcn_s_setprio(1);
#pragma unroll
        for (int mi = 0; mi < 4; mi++)
#pragma unroll
            for (int ni = 0; ni < 4; ni++)
                acc[mi][ni] = __builtin_amdgcn_mfma_f32_16x16x32_bf16(
                    aF[mi][1], bF[ni][1], acc[mi][ni], 0, 0, 0);
        __builtin_amdgcn_s_setprio(0);

        if (t < 15) {
            if (t < 14) asm volatile("s_waitcnt vmcnt(8)" ::: "memory");
            else        asm volatile("s_waitcnt vmcnt(0)" ::: "memory");
            __builtin_amdgcn_s_barrier();
        }
    }

#pragma unroll
    for (int ni = 0; ni < 4; ni++) {
        int col = colBase + wcN + ni * 16 + l15;
        float bv = bias[col];
#pragma unroll
        for (int mi = 0; mi < 4; mi++) {
            f32x4 a = acc[mi][ni];
#pragma unroll
            for (int r = 0; r < 4; r++) {
                int row = rowBase + wrM + mi * 16 + q4 * 4 + r;
                outf[(size_t)row * 1024 + col] =
                    a[r] + bv + bf2f(resid[(size_t)row * 1024 + col]);
            }
        }
    }
}

// ---------------------------------------------------------------------------
// Attention R19: one block = (head g, 128 q-rows); 8 waves x 16q; 512 thr.
// LDS 80 KB: Ks[2] + Vt[2] double-buffered + Ps.  2-deep counted-vmcnt
// pipeline (R15 recipe): per kt {QK^T, exp->Ps, PV, lgkm(0)+barrier,
// stage kt+2 -> buf[cur], vmcnt(4)+barrier}.  Never drains in steady state.
// setprio around both MFMA clusters (T5, attn-proven).
// XCD head-grouping swizzle: XCD x owns heads 8x..8x+7 (K/V working set
// 4MB/XCD instead of 32MB streamed through every L2).
//  - Ks [64 key][128 d], XOR-16 chunk swizzle
//  - Vt [128 d][64 key], XOR-8 chunk swizzle
//  - Ps [128 q][64 key], XOR-8 swizzle, wave-private rows (single buffer)
// ---------------------------------------------------------------------------
__device__ __forceinline__ void attn_stage(const ushort* __restrict__ Kh,
                                           const ushort* __restrict__ Vh,
                                           int kt, ushort* KsD, ushort* VtD,
                                           int tid) {
#pragma unroll
    for (int i = 0; i < 2; i++) {
        int linear = i * 512 + tid;          // 0..1023, wave-contiguous
        int r = linear >> 4, p = linear & 15;
        int l = p ^ (r & 15);
        gload_lds16(&Kh[(size_t)(kt * 64 + r) * 128 + l * 8], &KsD[linear * 8]);
    }
#pragma unroll
    for (int i = 0; i < 2; i++) {
        int linear = i * 512 + tid;          // 0..1023
        int d = linear >> 3, p = linear & 7;
        int c = p ^ (d & 7);
        gload_lds16(&Vh[(size_t)d * 1024 + kt * 64 + c * 8], &VtD[linear * 8]);
    }
}

__global__ __launch_bounds__(512) void attn_kernel(
    const ushort* __restrict__ qb, const ushort* __restrict__ kb,
    const ushort* __restrict__ vt, ushort* __restrict__ ob) {
    // XCD head-grouping: XCD x (bid&7) owns heads 8x..8x+7, all 8 q-blocks.
    int bid = blockIdx.x;
    int xcd = bid & 7, ii = bid >> 3;        // ii 0..63
    int g = xcd * 8 + (ii >> 3);             // head 0..63
    int qblk = ii & 7;                       // 128-row q block
    const ushort* Qh = qb + (size_t)g * 131072;
    const ushort* Kh = kb + (size_t)g * 131072;
    const ushort* Vh = vt + (size_t)g * 131072;  // [128 d][1024 key]

    __shared__ __align__(16) ushort Ks[2][64 * 128];   // 32 KB
    __shared__ __align__(16) ushort Vt[2][128 * 64];   // 32 KB
    __shared__ __align__(16) ushort Ps[128 * 64];      // 16 KB

    int tid = threadIdx.x, lane = tid & 63, w = tid >> 6;  // w in [0,8)
    int l15 = lane & 15, q4 = lane >> 4;
    int q0 = qblk * 128;

    // Q A-fragments: A[m=l15][k = ks*32 + q4*8 + j]
    short8 qf[4];
#pragma unroll
    for (int ks = 0; ks < 4; ks++)
        qf[ks] = *(const short8*)&Qh[(size_t)(q0 + w * 16 + l15) * 128 + ks * 32 + q4 * 8];

    f32x4 zero = {0.f, 0.f, 0.f, 0.f};
    f32x4 o[8];
#pragma unroll
    for (int ni = 0; ni < 8; ni++) o[ni] = zero;
    float plsum[4] = {0.f, 0.f, 0.f, 0.f};

    // prologue: stage kt0 -> buf0, kt1 -> buf1; wait only kt0 (4 left)
    attn_stage(Kh, Vh, 0, &Ks[0][0], &Vt[0][0], tid);
    attn_stage(Kh, Vh, 1, &Ks[1][0], &Vt[1][0], tid);
    asm volatile("s_waitcnt vmcnt(4)" ::: "memory");
    __builtin_amdgcn_s_barrier();

    for (int kt = 0; kt < 16; kt++) {
        const int cur = kt & 1;
        const ushort* Kc = &Ks[cur][0];
        const ushort* Vc = &Vt[cur][0];

        // S = Q K^T : 16q x 64key per wave
        f32x4 sacc[4];
#pragma unroll
        for (int ni = 0; ni < 4; ni++) sacc[ni] = zero;
        __builtin_amdgcn_s_setprio(1);
#pragma unroll
        for (int ks = 0; ks < 4; ks++) {
#pragma unroll
            for (int ni = 0; ni < 4; ni++) {
                int r = ni * 16 + l15;
                int p = (ks * 4 + q4) ^ (r & 15);
                short8 bF = *(const short8*)&Kc[r * 128 + p * 8];
                sacc[ni] = __builtin_amdgcn_mfma_f32_16x16x32_bf16(
                    qf[ks], bF, sacc[ni], 0, 0, 0);
            }
        }
        __builtin_amdgcn_s_setprio(0);

        // P = exp(S) -> Ps (swizzled); accumulate per-lane partial row sums
#pragma unroll
        for (int ni = 0; ni < 4; ni++) {
#pragma unroll
            for (int r = 0; r < 4; r++) {
                float pv = __expf(sacc[ni][r]);
                plsum[r] += pv;
                int qloc = w * 16 + q4 * 4 + r;       // wave-private rows
                int key = ni * 16 + l15;
                int pc = (key >> 3) ^ (qloc & 7);
                Ps[qloc * 64 + pc * 8 + (key & 7)] = f2bf(pv);
            }
        }

        // O += P V  (wave-private Ps rows; same-wave RAW handled by waitcnt)
        __builtin_amdgcn_s_setprio(1);
#pragma unroll
        for (int ks2 = 0; ks2 < 2; ks2++) {
            int c = ks2 * 4 + q4;
            int row = w * 16 + l15;                   // row&7 == l15&7
            short8 aF = *(const short8*)&Ps[row * 64 + (c ^ (l15 & 7)) * 8];
#pragma unroll
            for (int ni = 0; ni < 8; ni++) {
                int d = ni * 16 + l15;
                short8 bF = *(const short8*)&Vc[d * 64 + (c ^ (d & 7)) * 8];
                o[ni] = __builtin_amdgcn_mfma_f32_16x16x32_bf16(aF, bF, o[ni], 0, 0, 0);
            }
        }
        __builtin_amdgcn_s_setprio(0);

        // ---- all LDS reads of buf[cur] done -> restage; counted vmcnt ----
        asm volatile("s_waitcnt lgkmcnt(0)" ::: "memory");
        __builtin_amdgcn_s_barrier();
        if (kt < 14) attn_stage(Kh, Vh, kt + 2, &Ks[cur][0], &Vt[cur][0], tid);
        if (kt < 14)       asm volatile("s_waitcnt vmcnt(4)" ::: "memory");
        else if (kt == 14) asm volatile("s_waitcnt vmcnt(0)" ::: "memory");
        if (kt < 15) __builtin_amdgcn_s_barrier();
    }

    // row sums: reduce per-lane partials over the 16 l15-lanes
#pragma unroll
    for (int r = 0; r < 4; r++) {
#pragma unroll
        for (int m = 1; m < 16; m <<= 1) plsum[r] += __shfl_xor(plsum[r], m, 16);
    }
    float inv[4];
#pragma unroll
    for (int r = 0; r < 4; r++) inv[r] = 1.0f / plsum[r];
#pragma unroll
    for (int ni = 0; ni < 8; ni++)
#pragma unroll
        for (int r = 0; r < 4; r++) {
            int qrow = q0 + w * 16 + q4 * 4 + r;
            ob[(size_t)g * 131072 + (size_t)qrow * 128 + ni * 16 + l15] =
                f2bf(o[ni][r] * inv[r]);
        }
}

// ---------------------------------------------------------------------------
extern "C" void kernel_launch(void* const* d_in, const int* in_sizes, int n_in,
                              void* d_out, int out_size, void* d_ws, size_t ws_size,
                              hipStream_t stream) {
    const float* x     = (const float*)d_in[0];
    const float* ln_g  = (const float*)d_in[1];
    const float* ln_b  = (const float*)d_in[2];
    const float* w_qkv = (const float*)d_in[3];
    const float* b_qkv = (const float*)d_in[4];
    const float* w_out = (const float*)d_in[5];
    const float* b_out = (const float*)d_in[6];
    float* out = (float*)d_out;

    const size_t MC = 8192ull * 1024ull;  // 8.39M elems
    ushort* xn    = (ushort*)d_ws;
    ushort* wqkvT = xn + MC;
    ushort* woutT = wqkvT + 3072ull * 1024ull;
    ushort* qbuf  = woutT + 1024ull * 1024ull;
    ushort* kbuf  = qbuf + MC;
    ushort* vtbuf = kbuf + MC;        // V^T [64 heads][128 d][1024 seq]
    ushort* attnb = vtbuf + MC;       // scratch for raw V, then attn output
    // total: 46.14M ushorts = 92.3 MB (same layout as passing rounds 2-10)

    prep_kernel<<<6144, 256, 0, stream>>>(x, ln_g, ln_b, xn, w_qkv, wqkvT, w_out, woutT);
    // q,k -> qbuf,kbuf ; v -> attnb (scratch, row-major coalesced)
    gemm_qkv<<<1536, 256, 0, stream>>>(xn, wqkvT, b_qkv, qbuf, kbuf, attnb);
    transpose_head<<<dim3(4, 32, 64), 256, 0, stream>>>(attnb, vtbuf);
    attn_kernel<<<512, 512, 0, stream>>>(qbuf, kbuf, vtbuf, attnb);
    gemm_out<<<512, 256, 0, stream>>>(attnb, woutT, b_out, xn, out);
}